// Round 4
// baseline (419.007 us; speedup 1.0000x reference)
//
#include <hip/hip_runtime.h>
#include <hip/hip_bf16.h>

#define NV 256                 // V
#define NC 64                  // C_OUT
#define VW 65536               // V*V
#define NE1 1048576            // N*C*V = 2^20

typedef __attribute__((ext_vector_type(8))) short bf16x8;   // 8 bf16 = 4 VGPRs
typedef __attribute__((ext_vector_type(16))) float f32x16;  // MFMA 32x32 acc
typedef __attribute__((ext_vector_type(2))) unsigned int uint2v;

static __device__ __forceinline__ short f2bf(float x) {
    union { __hip_bfloat16 b; short s; } u;
    u.b = __float2bfloat16(x);          // RNE
    return u.s;
}
static __device__ __forceinline__ unsigned int pack2(float a, float b) {
    return (unsigned int)(unsigned short)f2bf(a) |
           ((unsigned int)(unsigned short)f2bf(b) << 16);
}

// ---------------------------------------------------------------------------
// k1: xo_c[n][c][v] = bo[c] + sum_i wo[c][i] * xo[n][i][v]
// ---------------------------------------------------------------------------
__global__ __launch_bounds__(256) void k1_xoc(
    const float* __restrict__ xo, const float* __restrict__ wo,
    const float* __restrict__ bo, float* __restrict__ xoc)
{
    const int idx = blockIdx.x * 256 + threadIdx.x;   // < 2^20
    const int v = idx & 255;
    const int c = (idx >> 8) & 63;
    const int n = idx >> 14;
    const float* xon = xo + (size_t)n * 64 * NV;
    const float* wrow = wo + c * 64;                  // block-uniform -> s_load
    float s = bo[c];
#pragma unroll
    for (int i = 0; i < 64; ++i)
        s = fmaf(wrow[i], xon[i * NV + v], s);
    xoc[idx] = s;
}

// ---------------------------------------------------------------------------
// k2: barrier-free MLP+MFMA. Each lane runs layers 1-2 (uniform SGPR weights)
// for ONE position (v, w = wt*64+lane), packs h2 to bf16 pairs in-register.
// B-fragments for mfma_f32_32x32x16_bf16 are built with 8 permlane32_swap
// (T12 pattern): swap(h2p[8h+j], h2p[8h+4+j]) -> {T0 chunk j, T1 chunk j}.
// No h2 LDS, no per-vi barriers; waves fully independent after xoc stage.
// Layer 3: D[32c x 32pos] = W3 @ H2 (K=32 via 2 chained MFMA), fused
// sigmoid + coalesced A_out store + gate accumulation from LDS broadcasts.
// Block = 4 waves (w-tiles of 64) x 16-v chunk; grid = (16, 64).
// ---------------------------------------------------------------------------
__global__ __launch_bounds__(256) void k2_mfma(
    const float* __restrict__ A,
    const float* __restrict__ w1, const float* __restrict__ b1,
    const float* __restrict__ w2, const float* __restrict__ b2,
    const float* __restrict__ w3, const float* __restrict__ b3,
    const float* __restrict__ xoc,
    float* __restrict__ Aout, float* __restrict__ post)
{
    __shared__ float xocs[NC][16];               // 4 KB

    const int t    = threadIdx.x;
    const int wt   = t >> 6;                     // wave id = w-tile
    const int lane = t & 63;
    const int lo   = lane & 31;
    const int hi   = lane >> 5;
    const int vbase = blockIdx.x * 16;
    const int n    = blockIdx.y;
    const int w0   = wt << 6;                    // wave's w base

    // ---- stage xoc[n, :, vbase:vbase+16] into LDS (once per block)
    {
        const int c = t >> 2, j0 = (t & 3) << 2;
        const float* src = xoc + (size_t)n * (NC * NV) + c * NV + vbase + j0;
#pragma unroll
        for (int j = 0; j < 4; ++j) xocs[c][j0 + j] = src[j];
    }
    __syncthreads();                             // the only barrier

    // ---- W3 A-fragments: lane(lo,hi) holds w3[c=32ct+lo][k=16h+8hi+e]
    bf16x8 af[2][2];
#pragma unroll
    for (int ct = 0; ct < 2; ++ct)
#pragma unroll
        for (int h = 0; h < 2; ++h) {
            const float* wp = w3 + ((ct << 5) + lo) * 32 + (h << 4) + (hi << 3);
            bf16x8 pk;
#pragma unroll
            for (int e = 0; e < 8; ++e) pk[e] = f2bf(wp[e]);
            af[ct][h] = pk;
        }

    // ---- bias as accumulator-init: dinit[ct][r] = b3[c(ct,r,hi)]
    f32x16 dinit[2];
#pragma unroll
    for (int ct = 0; ct < 2; ++ct)
#pragma unroll
        for (int r = 0; r < 16; ++r)
            dinit[ct][r] = b3[(ct << 5) + (r & 3) + ((r >> 2) << 3) + (hi << 2)];

    float gacc[2][2][16];
#pragma unroll
    for (int ct = 0; ct < 2; ++ct)
#pragma unroll
        for (int T = 0; T < 2; ++T)
#pragma unroll
            for (int r = 0; r < 16; ++r) gacc[ct][T][r] = 0.0f;

    const float* An  = A    + (size_t)n * 6 * VW;
    float*       Aon = Aout + (size_t)n * NC * VW;

    for (int vi = 0; vi < 16; ++vi) {
        const int v = vbase + vi;

        // ===== layers 1-2 for position (v, w0+lane); weights are SGPR =====
        const float* ap = An + (size_t)v * NV + w0 + lane;  // 256B coalesced
        const float a0 = ap[0];
        const float a1 = ap[VW];
        const float a2 = ap[2 * VW];
        const float a3 = ap[3 * VW];
        const float a4 = ap[4 * VW];

        float h1v[16];
#pragma unroll
        for (int j = 0; j < 16; ++j) {
            float s = b1[j];
            s = fmaf(w1[j * 5 + 0], a0, s);
            s = fmaf(w1[j * 5 + 1], a1, s);
            s = fmaf(w1[j * 5 + 2], a2, s);
            s = fmaf(w1[j * 5 + 3], a3, s);
            s = fmaf(w1[j * 5 + 4], a4, s);
            h1v[j] = fmaxf(s, 0.0f);
        }
        // h2 packed to bf16 pairs: h2p[m] = (h2[2m], h2[2m+1])
        unsigned int h2p[16];
#pragma unroll
        for (int m = 0; m < 16; ++m) {
            float sa = b2[(2 * m) * 16 + 0 ? 0 : 0];  // placeholder removed below
            sa = b2[2 * m];
            float sb = b2[2 * m + 1];
#pragma unroll
            for (int i = 0; i < 16; ++i) {
                sa = fmaf(w2[(2 * m) * 16 + i],     h1v[i], sa);
                sb = fmaf(w2[(2 * m + 1) * 16 + i], h1v[i], sb);
            }
            h2p[m] = pack2(fmaxf(sa, 0.0f), fmaxf(sb, 0.0f));
        }

        // ===== build B-fragments with permlane32_swap (both T at once) ====
        union { unsigned int u[4]; bf16x8 v8; } bT0[2], bT1[2];
#pragma unroll
        for (int h = 0; h < 2; ++h)
#pragma unroll
            for (int j = 0; j < 4; ++j) {
                uint2v r = __builtin_amdgcn_permlane32_swap(
                    h2p[8 * h + j], h2p[8 * h + 4 + j], false, false);
                bT0[h].u[j] = r.x;   // {A.lo, B.lo} -> positions 0..31
                bT1[h].u[j] = r.y;   // {A.hi, B.hi} -> positions 32..63
            }

        // ===== layer-3 MFMA + fused epilogue ==============================
#pragma unroll
        for (int ct = 0; ct < 2; ++ct)
#pragma unroll
            for (int T = 0; T < 2; ++T) {
                f32x16 d = dinit[ct];
                const bf16x8 bf0 = (T == 0) ? bT0[0].v8 : bT1[0].v8;
                const bf16x8 bf1 = (T == 0) ? bT0[1].v8 : bT1[1].v8;
                d = __builtin_amdgcn_mfma_f32_32x32x16_bf16(af[ct][0], bf0, d, 0, 0, 0);
                d = __builtin_amdgcn_mfma_f32_32x32x16_bf16(af[ct][1], bf1, d, 0, 0, 0);
                const int w = w0 + (T << 5) + lo;
                float* op = Aon + (size_t)v * NV + w;
#pragma unroll
                for (int r = 0; r < 16; ++r) {
                    // C/D: col=lane&31 (=pos), row=(r&3)+8*(r>>2)+4*hi (=c)
                    const int c = (ct << 5) + (r & 3) + ((r >> 2) << 3) + (hi << 2);
                    const float val = 1.0f / (1.0f + __expf(-d[r]));
                    op[(size_t)c * VW] = val;                      // 128B/half-wave
                    gacc[ct][T][r] = fmaf(xocs[c][vi], val, gacc[ct][T][r]);
                }
            }
    }

    // ---- gate: one atomic pass per block over its (c,w) tile
    float* pn = post + (size_t)n * (NC * NV);
#pragma unroll
    for (int ct = 0; ct < 2; ++ct)
#pragma unroll
        for (int T = 0; T < 2; ++T) {
            const int w = w0 + (T << 5) + lo;
#pragma unroll
            for (int r = 0; r < 16; ++r) {
                const int c = (ct << 5) + (r & 3) + ((r >> 2) << 3) + (hi << 2);
                atomicAdd(&pn[c * NV + w], gacc[ct][T][r]);
            }
        }
}

// ---------------------------------------------------------------------------
// k3: out1 = x * sigmoid(post)
// ---------------------------------------------------------------------------
__global__ __launch_bounds__(256) void k3_gate(
    const float* __restrict__ x, const float* __restrict__ post,
    float* __restrict__ out1)
{
    const int idx = blockIdx.x * 256 + threadIdx.x;
    const float p = 1.0f / (1.0f + __expf(-post[idx]));
    out1[idx] = x[idx] * p;
}

extern "C" void kernel_launch(void* const* d_in, const int* in_sizes, int n_in,
                              void* d_out, int out_size, void* d_ws, size_t ws_size,
                              hipStream_t stream)
{
    const float* x  = (const float*)d_in[0];
    const float* xo = (const float*)d_in[1];
    const float* A  = (const float*)d_in[2];
    const float* w1 = (const float*)d_in[3];
    const float* b1 = (const float*)d_in[4];
    const float* w2 = (const float*)d_in[5];
    const float* b2 = (const float*)d_in[6];
    const float* w3 = (const float*)d_in[7];
    const float* b3 = (const float*)d_in[8];
    const float* wo = (const float*)d_in[9];
    const float* bo = (const float*)d_in[10];

    float* out1 = (float*)d_out;
    float* Aout = (float*)d_out + NE1;

    float* xoc  = (float*)d_ws;
    float* post = (float*)d_ws + NE1;

    hipMemsetAsync(post, 0, (size_t)NE1 * sizeof(float), stream);
    k1_xoc<<<NE1 / 256, 256, 0, stream>>>(xo, wo, bo, xoc);
    k2_mfma<<<dim3(16, 64), 256, 0, stream>>>(A, w1, b1, w2, b2, w3, b3,
                                              xoc, Aout, post);
    k3_gate<<<NE1 / 256, 256, 0, stream>>>(x, post, out1);
}

// Round 5
// 287.648 us; speedup vs baseline: 1.4567x; 1.4567x over previous
//
#include <hip/hip_runtime.h>
#include <hip/hip_bf16.h>

#define NV 256                 // V
#define NC 64                  // C_OUT
#define VW 65536               // V*V
#define NE1 1048576            // N*C*V = 2^20
#define VB 8                   // v-chunk per block

typedef __attribute__((ext_vector_type(8))) short bf16x8;   // 8 bf16 = 4 VGPRs
typedef __attribute__((ext_vector_type(16))) float f32x16;  // MFMA 32x32 acc
typedef __attribute__((ext_vector_type(2))) unsigned int uint2v;

union fu32 { float f; unsigned int u; };

static __device__ __forceinline__ short f2bf(float x) {     // weights only
    union { __hip_bfloat16 b; short s; } u;
    u.b = __float2bfloat16(x);
    return u.s;
}
// one-inst RNE pack of two f32 -> 2xbf16 (T12 primitive, m214v22)
static __device__ __forceinline__ unsigned int cvt_pk_bf16(float a, float b) {
    unsigned int r;
    asm("v_cvt_pk_bf16_f32 %0, %1, %2" : "=v"(r) : "v"(a), "v"(b));
    return r;
}

// ---------------------------------------------------------------------------
// k1: xo_c[n][c][v] = bo[c] + sum_i wo[c][i] * xo[n][i][v]
// ---------------------------------------------------------------------------
__global__ __launch_bounds__(256) void k1_xoc(
    const float* __restrict__ xo, const float* __restrict__ wo,
    const float* __restrict__ bo, float* __restrict__ xoc)
{
    const int idx = blockIdx.x * 256 + threadIdx.x;   // < 2^20
    const int v = idx & 255;
    const int c = (idx >> 8) & 63;
    const int n = idx >> 14;
    const float* xon = xo + (size_t)n * 64 * NV;
    const float* wrow = wo + c * 64;                  // block-uniform -> s_load
    float s = bo[c];
#pragma unroll
    for (int i = 0; i < 64; ++i)
        s = fmaf(wrow[i], xon[i * NV + v], s);
    xoc[idx] = s;
}

// ---------------------------------------------------------------------------
// k2: lane = one position (v, w0+lane) for layers 1-2 (SGPR weights,
// cvt_pk bf16 pack); permlane32_swap builds MFMA B-fragments in-register;
// layer 3 = 32x32x16 bf16 MFMA pairs. NEW: D tiles T0/T1 are merged with a
// second permlane32_swap so each store is a FULL w-row: 256B contiguous,
// ascending-c streams (was 2x128B at 256KB separation). Bias is folded as a
// per-row scalar into the exp2 argument; sigmoid = v_rcp(1+v_exp2(fma)).
// Block = 4 waves x VB=8 v; grid = (32, 64).
// ---------------------------------------------------------------------------
__global__ __launch_bounds__(256) void k2_mfma(
    const float* __restrict__ A,
    const float* __restrict__ w1, const float* __restrict__ b1,
    const float* __restrict__ w2, const float* __restrict__ b2,
    const float* __restrict__ w3, const float* __restrict__ b3,
    const float* __restrict__ xoc,
    float* __restrict__ Aout, float* __restrict__ post)
{
    __shared__ float xocs[NC][VB];               // 2 KB

    const int t    = threadIdx.x;
    const int wt   = t >> 6;
    const int lane = t & 63;
    const int lo   = lane & 31;
    const int hi   = lane >> 5;
    const int vbase = blockIdx.x * VB;
    const int n    = blockIdx.y;
    const int w0   = wt << 6;

    for (int e = t; e < NC * VB; e += 256) {
        const int c = e >> 3, j = e & (VB - 1);
        xocs[c][j] = xoc[(size_t)n * (NC * NV) + c * NV + vbase + j];
    }
    __syncthreads();                             // the only barrier

    // W3 A-fragments: lane(lo,hi) holds w3[c=32ct+lo][k=16h+8hi+e]
    bf16x8 af[2][2];
#pragma unroll
    for (int ct = 0; ct < 2; ++ct)
#pragma unroll
        for (int h = 0; h < 2; ++h) {
            const float* wp = w3 + ((ct << 5) + lo) * 32 + (h << 4) + (hi << 3);
            bf16x8 pk;
#pragma unroll
            for (int e = 0; e < 8; ++e) pk[e] = f2bf(wp[e]);
            af[ct][h] = pk;
        }

    float gacc[2][16][2];
#pragma unroll
    for (int ct = 0; ct < 2; ++ct)
#pragma unroll
        for (int r = 0; r < 16; ++r) {
            gacc[ct][r][0] = 0.0f;
            gacc[ct][r][1] = 0.0f;
        }

    const float* An  = A    + (size_t)n * 6 * VW;
    float*       Aon = Aout + (size_t)n * NC * VW;
    const float NLOG2E = -1.4426950408889634f;

    for (int vi = 0; vi < VB; ++vi) {
        const int v = vbase + vi;

        // ===== layers 1-2 for position (v, w0+lane); weights are SGPR =====
        const float* ap = An + (size_t)v * NV + w0 + lane;  // 256B coalesced
        const float a0 = ap[0];
        const float a1 = ap[VW];
        const float a2 = ap[2 * VW];
        const float a3 = ap[3 * VW];
        const float a4 = ap[4 * VW];

        float h1v[16];
#pragma unroll
        for (int j = 0; j < 16; ++j) {
            float s = b1[j];
            s = fmaf(w1[j * 5 + 0], a0, s);
            s = fmaf(w1[j * 5 + 1], a1, s);
            s = fmaf(w1[j * 5 + 2], a2, s);
            s = fmaf(w1[j * 5 + 3], a3, s);
            s = fmaf(w1[j * 5 + 4], a4, s);
            h1v[j] = fmaxf(s, 0.0f);
        }
        unsigned int h2p[16];                    // h2p[m] = bf16(h2[2m],h2[2m+1])
#pragma unroll
        for (int m = 0; m < 16; ++m) {
            float sa = b2[2 * m];
            float sb = b2[2 * m + 1];
#pragma unroll
            for (int i = 0; i < 16; ++i) {
                sa = fmaf(w2[(2 * m) * 16 + i],     h1v[i], sa);
                sb = fmaf(w2[(2 * m + 1) * 16 + i], h1v[i], sb);
            }
            h2p[m] = cvt_pk_bf16(fmaxf(sa, 0.0f), fmaxf(sb, 0.0f));
        }

        // ===== B-fragments via permlane32_swap (both T tiles at once) =====
        union { unsigned int u[4]; bf16x8 v8; } bT0[2], bT1[2];
#pragma unroll
        for (int h = 0; h < 2; ++h)
#pragma unroll
            for (int j = 0; j < 4; ++j) {
                uint2v r = __builtin_amdgcn_permlane32_swap(
                    h2p[8 * h + j], h2p[8 * h + 4 + j], false, false);
                bT0[h].u[j] = r.x;
                bT1[h].u[j] = r.y;
            }

        float* rowp = Aon + (size_t)v * NV + w0 + lane;

        // ===== layer-3 MFMA; merge T0/T1 into full w-rows; fused epilogue ==
#pragma unroll
        for (int ct = 0; ct < 2; ++ct) {
            f32x16 d0, d1;
#pragma unroll
            for (int r = 0; r < 16; ++r) { d0[r] = 0.0f; d1[r] = 0.0f; }
            d0 = __builtin_amdgcn_mfma_f32_32x32x16_bf16(af[ct][0], bT0[0].v8, d0, 0, 0, 0);
            d0 = __builtin_amdgcn_mfma_f32_32x32x16_bf16(af[ct][1], bT0[1].v8, d0, 0, 0, 0);
            d1 = __builtin_amdgcn_mfma_f32_32x32x16_bf16(af[ct][0], bT1[0].v8, d1, 0, 0, 0);
            d1 = __builtin_amdgcn_mfma_f32_32x32x16_bf16(af[ct][1], bT1[1].v8, d1, 0, 0, 0);
#pragma unroll
            for (int r = 0; r < 16; ++r) {
                const int cx = (ct << 5) + (r & 3) + ((r >> 2) << 3);  // hi=0 row
                const int cy = cx + 4;                                  // hi=1 row
                fu32 ux, uy, mx, my;
                ux.f = d0[r]; uy.f = d1[r];
                uint2v m = __builtin_amdgcn_permlane32_swap(ux.u, uy.u, false, false);
                mx.u = m.x; my.u = m.y;     // mx: row cx, w=w0+lane; my: row cy
                const float vx = __builtin_amdgcn_rcpf(
                    1.0f + __builtin_amdgcn_exp2f(fmaf(mx.f, NLOG2E, b3[cx] * NLOG2E)));
                const float vy = __builtin_amdgcn_rcpf(
                    1.0f + __builtin_amdgcn_exp2f(fmaf(my.f, NLOG2E, b3[cy] * NLOG2E)));
                __builtin_nontemporal_store(vx, rowp + (size_t)cx * VW);  // 256B contig
                __builtin_nontemporal_store(vy, rowp + (size_t)cy * VW);
                gacc[ct][r][0] = fmaf(xocs[cx][vi], vx, gacc[ct][r][0]);
                gacc[ct][r][1] = fmaf(xocs[cy][vi], vy, gacc[ct][r][1]);
            }
        }
    }

    // ---- gate: one atomic pass per block; 256B contiguous per inst
    float* pn = post + (size_t)n * (NC * NV) + w0 + lane;
#pragma unroll
    for (int ct = 0; ct < 2; ++ct)
#pragma unroll
        for (int r = 0; r < 16; ++r) {
            const int cx = (ct << 5) + (r & 3) + ((r >> 2) << 3);
            atomicAdd(pn + cx * NV,       gacc[ct][r][0]);
            atomicAdd(pn + (cx + 4) * NV, gacc[ct][r][1]);
        }
}

// ---------------------------------------------------------------------------
// k3: out1 = x * sigmoid(post)
// ---------------------------------------------------------------------------
__global__ __launch_bounds__(256) void k3_gate(
    const float* __restrict__ x, const float* __restrict__ post,
    float* __restrict__ out1)
{
    const int idx = blockIdx.x * 256 + threadIdx.x;
    const float p = 1.0f / (1.0f + __expf(-post[idx]));
    out1[idx] = x[idx] * p;
}

extern "C" void kernel_launch(void* const* d_in, const int* in_sizes, int n_in,
                              void* d_out, int out_size, void* d_ws, size_t ws_size,
                              hipStream_t stream)
{
    const float* x  = (const float*)d_in[0];
    const float* xo = (const float*)d_in[1];
    const float* A  = (const float*)d_in[2];
    const float* w1 = (const float*)d_in[3];
    const float* b1 = (const float*)d_in[4];
    const float* w2 = (const float*)d_in[5];
    const float* b2 = (const float*)d_in[6];
    const float* w3 = (const float*)d_in[7];
    const float* b3 = (const float*)d_in[8];
    const float* wo = (const float*)d_in[9];
    const float* bo = (const float*)d_in[10];

    float* out1 = (float*)d_out;
    float* Aout = (float*)d_out + NE1;

    float* xoc  = (float*)d_ws;
    float* post = (float*)d_ws + NE1;

    hipMemsetAsync(post, 0, (size_t)NE1 * sizeof(float), stream);
    k1_xoc<<<NE1 / 256, 256, 0, stream>>>(xo, wo, bo, xoc);
    k2_mfma<<<dim3(NV / VB, 64), 256, 0, stream>>>(A, w1, b1, w2, b2, w3, b3,
                                                   xoc, Aout, post);
    k3_gate<<<NE1 / 256, 256, 0, stream>>>(x, post, out1);
}

// Round 6
// 281.160 us; speedup vs baseline: 1.4903x; 1.0231x over previous
//
#include <hip/hip_runtime.h>
#include <hip/hip_bf16.h>

#define NV 256                 // V
#define NC 64                  // C_OUT
#define VW 65536               // V*V
#define NE1 1048576            // N*C*V = 2^20
#define VB 8                   // v-chunk per block

typedef __attribute__((ext_vector_type(8))) short bf16x8;   // 8 bf16 = 4 VGPRs
typedef __attribute__((ext_vector_type(16))) float f32x16;  // MFMA 32x32 acc
typedef __attribute__((ext_vector_type(2))) unsigned int uint2v;

union fu32 { float f; unsigned int u; };
union U4 { unsigned int u[4]; bf16x8 v8; };

static __device__ __forceinline__ short f2bf(float x) {     // weights only
    union { __hip_bfloat16 b; short s; } u;
    u.b = __float2bfloat16(x);
    return u.s;
}
// one-inst RNE pack of two f32 -> 2xbf16
static __device__ __forceinline__ unsigned int cvt_pk_bf16(float a, float b) {
    unsigned int r;
    asm("v_cvt_pk_bf16_f32 %0, %1, %2" : "=v"(r) : "v"(a), "v"(b));
    return r;
}

// ---------------------------------------------------------------------------
// k1: xo_c[n][c][v] = bo[c] + sum_i wo[c][i] * xo[n][i][v]
// ---------------------------------------------------------------------------
__global__ __launch_bounds__(256) void k1_xoc(
    const float* __restrict__ xo, const float* __restrict__ wo,
    const float* __restrict__ bo, float* __restrict__ xoc)
{
    const int idx = blockIdx.x * 256 + threadIdx.x;   // < 2^20
    const int v = idx & 255;
    const int c = (idx >> 8) & 63;
    const int n = idx >> 14;
    const float* xon = xo + (size_t)n * 64 * NV;
    const float* wrow = wo + c * 64;                  // block-uniform -> s_load
    float s = bo[c];
#pragma unroll
    for (int i = 0; i < 64; ++i)
        s = fmaf(wrow[i], xon[i * NV + v], s);
    xoc[idx] = s;
}

// ---------------------------------------------------------------------------
// k2: lane = one position (v, w0+lane). Layer 1 (5->16) scalar VALU with
// SGPR weights; layer 2 (16->32) NOW on MFMA: h1 packed bf16 (relu folded
// into cvt_pk), permlane32_swap builds B1 tiles, D = W2 @ H1 + b2 (C-seed).
// Layer-3 B-fragments assembled from layer-2 D regs with 8 more swaps
// (hi-half row exchange). Layer 3 = 32x32x16 MFMA pairs; T0/T1 D-merge via
// swap -> full 256B w-row stores (nontemporal); sigmoid = rcp(1+exp2(fma)).
// A[vi+1] software-prefetched at loop top. Block = 4 waves x VB=8 v.
// ---------------------------------------------------------------------------
__global__ __launch_bounds__(256) void k2_mfma(
    const float* __restrict__ A,
    const float* __restrict__ w1, const float* __restrict__ b1,
    const float* __restrict__ w2, const float* __restrict__ b2,
    const float* __restrict__ w3, const float* __restrict__ b3,
    const float* __restrict__ xoc,
    float* __restrict__ Aout, float* __restrict__ post)
{
    __shared__ float xocs[NC][VB];               // 2 KB

    const int t    = threadIdx.x;
    const int wt   = t >> 6;
    const int lane = t & 63;
    const int lo   = lane & 31;
    const int hi   = lane >> 5;
    const int vbase = blockIdx.x * VB;
    const int n    = blockIdx.y;
    const int w0   = wt << 6;

    for (int e = t; e < NC * VB; e += 256) {
        const int c = e >> 3, j = e & (VB - 1);
        xocs[c][j] = xoc[(size_t)n * (NC * NV) + c * NV + vbase + j];
    }
    __syncthreads();                             // the only barrier

    // W3 A-fragments: lane(lo,hi) holds w3[c=32ct+lo][k=16h+8hi+e]
    bf16x8 af[2][2];
#pragma unroll
    for (int ct = 0; ct < 2; ++ct)
#pragma unroll
        for (int h = 0; h < 2; ++h) {
            const float* wp = w3 + ((ct << 5) + lo) * 32 + (h << 4) + (hi << 3);
            bf16x8 pk;
#pragma unroll
            for (int e = 0; e < 8; ++e) pk[e] = f2bf(wp[e]);
            af[ct][h] = pk;
        }
    // W2 A-fragment: lane(lo,hi) holds w2[row=lo][k=8hi+e]  (K=16)
    bf16x8 af2;
#pragma unroll
    for (int e = 0; e < 8; ++e) af2[e] = f2bf(w2[lo * 16 + (hi << 3) + e]);

    float gacc[2][16][2];
#pragma unroll
    for (int ct = 0; ct < 2; ++ct)
#pragma unroll
        for (int r = 0; r < 16; ++r) {
            gacc[ct][r][0] = 0.0f;
            gacc[ct][r][1] = 0.0f;
        }

    const float* An  = A    + (size_t)n * 6 * VW;
    float*       Aon = Aout + (size_t)n * NC * VW;
    const float NLOG2E = -1.4426950408889634f;

    // ---- software prefetch of the 5 A-planes for vi=0
    const float* ap0 = An + (size_t)vbase * NV + w0 + lane;
    float a0 = ap0[0], a1 = ap0[VW], a2 = ap0[2 * VW],
          a3 = ap0[3 * VW], a4 = ap0[4 * VW];

    for (int vi = 0; vi < VB; ++vi) {
        const int v = vbase + vi;

        // issue next-vi loads early (redundant re-load on last iter; uniform)
        const int vn = (vi + 1 < VB) ? (vi + 1) : vi;
        const float* apn = ap0 + (size_t)vn * NV;
        const float na0 = apn[0], na1 = apn[VW], na2 = apn[2 * VW],
                    na3 = apn[3 * VW], na4 = apn[4 * VW];

        // ===== layer 1 (5->16), scalar; weights are SGPR =====
        unsigned int h1p[8];                 // h1 packed bf16 pairs (relu'd)
#pragma unroll
        for (int m = 0; m < 8; ++m) {
            float sa = b1[2 * m];
            float sb = b1[2 * m + 1];
            sa = fmaf(w1[(2 * m) * 5 + 0], a0, sa);
            sa = fmaf(w1[(2 * m) * 5 + 1], a1, sa);
            sa = fmaf(w1[(2 * m) * 5 + 2], a2, sa);
            sa = fmaf(w1[(2 * m) * 5 + 3], a3, sa);
            sa = fmaf(w1[(2 * m) * 5 + 4], a4, sa);
            sb = fmaf(w1[(2 * m + 1) * 5 + 0], a0, sb);
            sb = fmaf(w1[(2 * m + 1) * 5 + 1], a1, sb);
            sb = fmaf(w1[(2 * m + 1) * 5 + 2], a2, sb);
            sb = fmaf(w1[(2 * m + 1) * 5 + 3], a3, sb);
            sb = fmaf(w1[(2 * m + 1) * 5 + 4], a4, sb);
            h1p[m] = cvt_pk_bf16(fmaxf(sa, 0.0f), fmaxf(sb, 0.0f));
        }

        // ===== layer 2 (16->32) on MFMA =====
        // B1 tiles via permlane32_swap: .x -> pos 0..31, .y -> pos 32..63
        U4 b1T0, b1T1;
#pragma unroll
        for (int j = 0; j < 4; ++j) {
            uint2v r = __builtin_amdgcn_permlane32_swap(h1p[j], h1p[4 + j],
                                                        false, false);
            b1T0.u[j] = r.x;
            b1T1.u[j] = r.y;
        }
        f32x16 d20, d21;                     // C seeded with b2 (D-row map)
#pragma unroll
        for (int r = 0; r < 16; ++r) {
            const float bv = b2[(r & 3) + ((r >> 2) << 3) + (hi << 2)];
            d20[r] = bv; d21[r] = bv;
        }
        d20 = __builtin_amdgcn_mfma_f32_32x32x16_bf16(af2, b1T0.v8, d20, 0, 0, 0);
        d21 = __builtin_amdgcn_mfma_f32_32x32x16_bf16(af2, b1T1.v8, d21, 0, 0, 0);

        // relu + pack: p[j]/q[j] = bf16 pair of h2 rows (2j&3)+8*(2j>>2)+{0,1}+4hi
        unsigned int p[8], q[8];
#pragma unroll
        for (int j = 0; j < 8; ++j) {
            p[j] = cvt_pk_bf16(fmaxf(d20[2 * j], 0.0f), fmaxf(d20[2 * j + 1], 0.0f));
            q[j] = cvt_pk_bf16(fmaxf(d21[2 * j], 0.0f), fmaxf(d21[2 * j + 1], 0.0f));
        }
        // L3 B-fragments: hi-half row exchange. b3f[T][h]:
        //   u0,u2 = swap(p[4h+0], p[4h+2]); u1,u3 = swap(p[4h+1], p[4h+3])
        U4 b3f[2][2];
#pragma unroll
        for (int h = 0; h < 2; ++h) {
            uint2v r02 = __builtin_amdgcn_permlane32_swap(p[4 * h + 0], p[4 * h + 2], false, false);
            uint2v r13 = __builtin_amdgcn_permlane32_swap(p[4 * h + 1], p[4 * h + 3], false, false);
            b3f[0][h].u[0] = r02.x; b3f[0][h].u[2] = r02.y;
            b3f[0][h].u[1] = r13.x; b3f[0][h].u[3] = r13.y;
            uint2v s02 = __builtin_amdgcn_permlane32_swap(q[4 * h + 0], q[4 * h + 2], false, false);
            uint2v s13 = __builtin_amdgcn_permlane32_swap(q[4 * h + 1], q[4 * h + 3], false, false);
            b3f[1][h].u[0] = s02.x; b3f[1][h].u[2] = s02.y;
            b3f[1][h].u[1] = s13.x; b3f[1][h].u[3] = s13.y;
        }

        float* rowp = Aon + (size_t)v * NV + w0 + lane;

        // ===== layer 3 MFMA; merge T0/T1 into full w-rows; fused epilogue ==
#pragma unroll
        for (int ct = 0; ct < 2; ++ct) {
            f32x16 d0, d1;
#pragma unroll
            for (int r = 0; r < 16; ++r) { d0[r] = 0.0f; d1[r] = 0.0f; }
            d0 = __builtin_amdgcn_mfma_f32_32x32x16_bf16(af[ct][0], b3f[0][0].v8, d0, 0, 0, 0);
            d0 = __builtin_amdgcn_mfma_f32_32x32x16_bf16(af[ct][1], b3f[0][1].v8, d0, 0, 0, 0);
            d1 = __builtin_amdgcn_mfma_f32_32x32x16_bf16(af[ct][0], b3f[1][0].v8, d1, 0, 0, 0);
            d1 = __builtin_amdgcn_mfma_f32_32x32x16_bf16(af[ct][1], b3f[1][1].v8, d1, 0, 0, 0);
#pragma unroll
            for (int r = 0; r < 16; ++r) {
                const int cx = (ct << 5) + (r & 3) + ((r >> 2) << 3);  // hi=0 row
                const int cy = cx + 4;                                  // hi=1 row
                fu32 ux, uy, mx, my;
                ux.f = d0[r]; uy.f = d1[r];
                uint2v m = __builtin_amdgcn_permlane32_swap(ux.u, uy.u, false, false);
                mx.u = m.x; my.u = m.y;     // mx: row cx, w=w0+lane; my: row cy
                const float vx = __builtin_amdgcn_rcpf(
                    1.0f + __builtin_amdgcn_exp2f(fmaf(mx.f, NLOG2E, b3[cx] * NLOG2E)));
                const float vy = __builtin_amdgcn_rcpf(
                    1.0f + __builtin_amdgcn_exp2f(fmaf(my.f, NLOG2E, b3[cy] * NLOG2E)));
                __builtin_nontemporal_store(vx, rowp + (size_t)cx * VW);  // 256B contig
                __builtin_nontemporal_store(vy, rowp + (size_t)cy * VW);
                gacc[ct][r][0] = fmaf(xocs[cx][vi], vx, gacc[ct][r][0]);
                gacc[ct][r][1] = fmaf(xocs[cy][vi], vy, gacc[ct][r][1]);
            }
        }

        a0 = na0; a1 = na1; a2 = na2; a3 = na3; a4 = na4;
    }

    // ---- gate: one atomic pass per block; 256B contiguous per inst
    float* pn = post + (size_t)n * (NC * NV) + w0 + lane;
#pragma unroll
    for (int ct = 0; ct < 2; ++ct)
#pragma unroll
        for (int r = 0; r < 16; ++r) {
            const int cx = (ct << 5) + (r & 3) + ((r >> 2) << 3);
            atomicAdd(pn + cx * NV,       gacc[ct][r][0]);
            atomicAdd(pn + (cx + 4) * NV, gacc[ct][r][1]);
        }
}

// ---------------------------------------------------------------------------
// k3: out1 = x * sigmoid(post)
// ---------------------------------------------------------------------------
__global__ __launch_bounds__(256) void k3_gate(
    const float* __restrict__ x, const float* __restrict__ post,
    float* __restrict__ out1)
{
    const int idx = blockIdx.x * 256 + threadIdx.x;
    const float p = 1.0f / (1.0f + __expf(-post[idx]));
    out1[idx] = x[idx] * p;
}

extern "C" void kernel_launch(void* const* d_in, const int* in_sizes, int n_in,
                              void* d_out, int out_size, void* d_ws, size_t ws_size,
                              hipStream_t stream)
{
    const float* x  = (const float*)d_in[0];
    const float* xo = (const float*)d_in[1];
    const float* A  = (const float*)d_in[2];
    const float* w1 = (const float*)d_in[3];
    const float* b1 = (const float*)d_in[4];
    const float* w2 = (const float*)d_in[5];
    const float* b2 = (const float*)d_in[6];
    const float* w3 = (const float*)d_in[7];
    const float* b3 = (const float*)d_in[8];
    const float* wo = (const float*)d_in[9];
    const float* bo = (const float*)d_in[10];

    float* out1 = (float*)d_out;
    float* Aout = (float*)d_out + NE1;

    float* xoc  = (float*)d_ws;
    float* post = (float*)d_ws + NE1;

    hipMemsetAsync(post, 0, (size_t)NE1 * sizeof(float), stream);
    k1_xoc<<<NE1 / 256, 256, 0, stream>>>(xo, wo, bo, xoc);
    k2_mfma<<<dim3(NV / VB, 64), 256, 0, stream>>>(A, w1, b1, w2, b2, w3, b3,
                                                   xoc, Aout, post);
    k3_gate<<<NE1 / 256, 256, 0, stream>>>(x, post, out1);
}

// Round 7
// 279.950 us; speedup vs baseline: 1.4967x; 1.0043x over previous
//
#include <hip/hip_runtime.h>
#include <hip/hip_bf16.h>

#define NV 256                 // V
#define NC 64                  // C_OUT
#define VW 65536               // V*V
#define NE1 1048576            // N*C*V = 2^20
#define VB 32                  // v-chunk per block -> grid 8x64 = 512 = 2/CU

typedef __attribute__((ext_vector_type(8))) short bf16x8;   // 8 bf16 = 4 VGPRs
typedef __attribute__((ext_vector_type(16))) float f32x16;  // MFMA 32x32 acc
typedef __attribute__((ext_vector_type(2))) unsigned int uint2v;

union fu32 { float f; unsigned int u; };
union U4 { unsigned int u[4]; bf16x8 v8; };

static __device__ __forceinline__ short f2bf(float x) {     // weights only
    union { __hip_bfloat16 b; short s; } u;
    u.b = __float2bfloat16(x);
    return u.s;
}
// one-inst RNE pack of two f32 -> 2xbf16
static __device__ __forceinline__ unsigned int cvt_pk_bf16(float a, float b) {
    unsigned int r;
    asm("v_cvt_pk_bf16_f32 %0, %1, %2" : "=v"(r) : "v"(a), "v"(b));
    return r;
}

// ---------------------------------------------------------------------------
// k1: xo_c[n][c][v] = bo[c] + sum_i wo[c][i] * xo[n][i][v]
// ---------------------------------------------------------------------------
__global__ __launch_bounds__(256) void k1_xoc(
    const float* __restrict__ xo, const float* __restrict__ wo,
    const float* __restrict__ bo, float* __restrict__ xoc)
{
    const int idx = blockIdx.x * 256 + threadIdx.x;   // < 2^20
    const int v = idx & 255;
    const int c = (idx >> 8) & 63;
    const int n = idx >> 14;
    const float* xon = xo + (size_t)n * 64 * NV;
    const float* wrow = wo + c * 64;                  // block-uniform -> s_load
    float s = bo[c];
#pragma unroll
    for (int i = 0; i < 64; ++i)
        s = fmaf(wrow[i], xon[i * NV + v], s);
    xoc[idx] = s;
}

// ---------------------------------------------------------------------------
// k2: lane = one position (v, w0+lane). L1 scalar (SGPR weights); L2 and L3
// on 32x32x16 bf16 MFMA with permlane32_swap fragment assembly (R5/R6
// verified); T0/T1 D-merge -> full 256B w-row nontemporal stores; sigmoid =
// rcp(1+exp2(fma)). Gate partials: USE_PART ? plain stores to a per-block
// gpart slice (no atomics) : one atomicAdd pass. Block = 4 waves x VB=32 v;
// grid = (8, 64) = 512 blocks = exactly 2 resident/CU (one static round).
// ---------------------------------------------------------------------------
template <bool USE_PART>
__global__ __launch_bounds__(256) void k2_mfma(
    const float* __restrict__ A,
    const float* __restrict__ w1, const float* __restrict__ b1,
    const float* __restrict__ w2, const float* __restrict__ b2,
    const float* __restrict__ w3, const float* __restrict__ b3,
    const float* __restrict__ xoc,
    float* __restrict__ Aout, float* __restrict__ gout)
{
    __shared__ float xocs[NC][VB];               // 8 KB

    const int t    = threadIdx.x;
    const int wt   = t >> 6;
    const int lane = t & 63;
    const int lo   = lane & 31;
    const int hi   = lane >> 5;
    const int vbase = blockIdx.x * VB;
    const int n    = blockIdx.y;
    const int w0   = wt << 6;

    for (int e = t; e < NC * VB; e += 256) {
        const int c = e >> 5, j = e & (VB - 1);
        xocs[c][j] = xoc[(size_t)n * (NC * NV) + c * NV + vbase + j];
    }
    __syncthreads();                             // the only barrier

    // W3 A-fragments: lane(lo,hi) holds w3[c=32ct+lo][k=16h+8hi+e]
    bf16x8 af[2][2];
#pragma unroll
    for (int ct = 0; ct < 2; ++ct)
#pragma unroll
        for (int h = 0; h < 2; ++h) {
            const float* wp = w3 + ((ct << 5) + lo) * 32 + (h << 4) + (hi << 3);
            bf16x8 pk;
#pragma unroll
            for (int e = 0; e < 8; ++e) pk[e] = f2bf(wp[e]);
            af[ct][h] = pk;
        }
    // W2 A-fragment: lane(lo,hi) holds w2[row=lo][k=8hi+e]  (K=16)
    bf16x8 af2;
#pragma unroll
    for (int e = 0; e < 8; ++e) af2[e] = f2bf(w2[lo * 16 + (hi << 3) + e]);

    float gacc[2][16][2];
#pragma unroll
    for (int ct = 0; ct < 2; ++ct)
#pragma unroll
        for (int r = 0; r < 16; ++r) {
            gacc[ct][r][0] = 0.0f;
            gacc[ct][r][1] = 0.0f;
        }

    const float* An  = A    + (size_t)n * 6 * VW;
    float*       Aon = Aout + (size_t)n * NC * VW;
    const float NLOG2E = -1.4426950408889634f;

    // ---- software prefetch of the 5 A-planes for vi=0
    const float* ap0 = An + (size_t)vbase * NV + w0 + lane;
    float a0 = ap0[0], a1 = ap0[VW], a2 = ap0[2 * VW],
          a3 = ap0[3 * VW], a4 = ap0[4 * VW];

    for (int vi = 0; vi < VB; ++vi) {
        const int v = vbase + vi;

        // issue next-vi loads early (redundant re-load on last iter; uniform)
        const int vn = (vi + 1 < VB) ? (vi + 1) : vi;
        const float* apn = ap0 + (size_t)vn * NV;
        const float na0 = apn[0], na1 = apn[VW], na2 = apn[2 * VW],
                    na3 = apn[3 * VW], na4 = apn[4 * VW];

        // ===== layer 1 (5->16), scalar; weights are SGPR =====
        unsigned int h1p[8];                 // h1 packed bf16 pairs (relu'd)
#pragma unroll
        for (int m = 0; m < 8; ++m) {
            float sa = b1[2 * m];
            float sb = b1[2 * m + 1];
            sa = fmaf(w1[(2 * m) * 5 + 0], a0, sa);
            sa = fmaf(w1[(2 * m) * 5 + 1], a1, sa);
            sa = fmaf(w1[(2 * m) * 5 + 2], a2, sa);
            sa = fmaf(w1[(2 * m) * 5 + 3], a3, sa);
            sa = fmaf(w1[(2 * m) * 5 + 4], a4, sa);
            sb = fmaf(w1[(2 * m + 1) * 5 + 0], a0, sb);
            sb = fmaf(w1[(2 * m + 1) * 5 + 1], a1, sb);
            sb = fmaf(w1[(2 * m + 1) * 5 + 2], a2, sb);
            sb = fmaf(w1[(2 * m + 1) * 5 + 3], a3, sb);
            sb = fmaf(w1[(2 * m + 1) * 5 + 4], a4, sb);
            h1p[m] = cvt_pk_bf16(fmaxf(sa, 0.0f), fmaxf(sb, 0.0f));
        }

        // ===== layer 2 (16->32) on MFMA =====
        U4 b1T0, b1T1;
#pragma unroll
        for (int j = 0; j < 4; ++j) {
            uint2v r = __builtin_amdgcn_permlane32_swap(h1p[j], h1p[4 + j],
                                                        false, false);
            b1T0.u[j] = r.x;
            b1T1.u[j] = r.y;
        }
        f32x16 d20, d21;                     // C seeded with b2 (D-row map)
#pragma unroll
        for (int r = 0; r < 16; ++r) {
            const float bv = b2[(r & 3) + ((r >> 2) << 3) + (hi << 2)];
            d20[r] = bv; d21[r] = bv;
        }
        d20 = __builtin_amdgcn_mfma_f32_32x32x16_bf16(af2, b1T0.v8, d20, 0, 0, 0);
        d21 = __builtin_amdgcn_mfma_f32_32x32x16_bf16(af2, b1T1.v8, d21, 0, 0, 0);

        unsigned int p[8], q[8];
#pragma unroll
        for (int j = 0; j < 8; ++j) {
            p[j] = cvt_pk_bf16(fmaxf(d20[2 * j], 0.0f), fmaxf(d20[2 * j + 1], 0.0f));
            q[j] = cvt_pk_bf16(fmaxf(d21[2 * j], 0.0f), fmaxf(d21[2 * j + 1], 0.0f));
        }
        // L3 B-fragments: hi-half row exchange
        U4 b3f[2][2];
#pragma unroll
        for (int h = 0; h < 2; ++h) {
            uint2v r02 = __builtin_amdgcn_permlane32_swap(p[4 * h + 0], p[4 * h + 2], false, false);
            uint2v r13 = __builtin_amdgcn_permlane32_swap(p[4 * h + 1], p[4 * h + 3], false, false);
            b3f[0][h].u[0] = r02.x; b3f[0][h].u[2] = r02.y;
            b3f[0][h].u[1] = r13.x; b3f[0][h].u[3] = r13.y;
            uint2v s02 = __builtin_amdgcn_permlane32_swap(q[4 * h + 0], q[4 * h + 2], false, false);
            uint2v s13 = __builtin_amdgcn_permlane32_swap(q[4 * h + 1], q[4 * h + 3], false, false);
            b3f[1][h].u[0] = s02.x; b3f[1][h].u[2] = s02.y;
            b3f[1][h].u[1] = s13.x; b3f[1][h].u[3] = s13.y;
        }

        float* rowp = Aon + (size_t)v * NV + w0 + lane;

        // ===== layer 3 MFMA; merge T0/T1 into full w-rows; fused epilogue ==
#pragma unroll
        for (int ct = 0; ct < 2; ++ct) {
            f32x16 d0, d1;
#pragma unroll
            for (int r = 0; r < 16; ++r) { d0[r] = 0.0f; d1[r] = 0.0f; }
            d0 = __builtin_amdgcn_mfma_f32_32x32x16_bf16(af[ct][0], b3f[0][0].v8, d0, 0, 0, 0);
            d0 = __builtin_amdgcn_mfma_f32_32x32x16_bf16(af[ct][1], b3f[0][1].v8, d0, 0, 0, 0);
            d1 = __builtin_amdgcn_mfma_f32_32x32x16_bf16(af[ct][0], b3f[1][0].v8, d1, 0, 0, 0);
            d1 = __builtin_amdgcn_mfma_f32_32x32x16_bf16(af[ct][1], b3f[1][1].v8, d1, 0, 0, 0);
#pragma unroll
            for (int r = 0; r < 16; ++r) {
                const int cx = (ct << 5) + (r & 3) + ((r >> 2) << 3);  // hi=0 row
                const int cy = cx + 4;                                  // hi=1 row
                fu32 ux, uy, mx, my;
                ux.f = d0[r]; uy.f = d1[r];
                uint2v m = __builtin_amdgcn_permlane32_swap(ux.u, uy.u, false, false);
                mx.u = m.x; my.u = m.y;     // mx: row cx, w=w0+lane; my: row cy
                const float vx = __builtin_amdgcn_rcpf(
                    1.0f + __builtin_amdgcn_exp2f(fmaf(mx.f, NLOG2E, b3[cx] * NLOG2E)));
                const float vy = __builtin_amdgcn_rcpf(
                    1.0f + __builtin_amdgcn_exp2f(fmaf(my.f, NLOG2E, b3[cy] * NLOG2E)));
                __builtin_nontemporal_store(vx, rowp + (size_t)cx * VW);  // 256B contig
                __builtin_nontemporal_store(vy, rowp + (size_t)cy * VW);
                gacc[ct][r][0] = fmaf(xocs[cx][vi], vx, gacc[ct][r][0]);
                gacc[ct][r][1] = fmaf(xocs[cy][vi], vy, gacc[ct][r][1]);
            }
        }

        a0 = na0; a1 = na1; a2 = na2; a3 = na3; a4 = na4;
    }

    // ---- gate partials: per-block private slice (plain) or atomic pass
    if (USE_PART) {
        float* gp = gout + (size_t)blockIdx.x * NE1
                         + (size_t)n * (NC * NV) + w0 + lane;
#pragma unroll
        for (int ct = 0; ct < 2; ++ct)
#pragma unroll
            for (int r = 0; r < 16; ++r) {
                const int cx = (ct << 5) + (r & 3) + ((r >> 2) << 3);
                gp[cx * NV]       = gacc[ct][r][0];
                gp[(cx + 4) * NV] = gacc[ct][r][1];
            }
    } else {
        float* pn = gout + (size_t)n * (NC * NV) + w0 + lane;
#pragma unroll
        for (int ct = 0; ct < 2; ++ct)
#pragma unroll
            for (int r = 0; r < 16; ++r) {
                const int cx = (ct << 5) + (r & 3) + ((r >> 2) << 3);
                atomicAdd(pn + cx * NV,       gacc[ct][r][0]);
                atomicAdd(pn + (cx + 4) * NV, gacc[ct][r][1]);
            }
    }
}

// ---------------------------------------------------------------------------
// k3: out1 = x * sigmoid(sum of gate partials)   (USE_PART: 8 slices; else
// the pre-reduced atomic buffer)
// ---------------------------------------------------------------------------
template <bool USE_PART>
__global__ __launch_bounds__(256) void k3_gate(
    const float* __restrict__ x, const float* __restrict__ g,
    float* __restrict__ out1)
{
    const int idx = blockIdx.x * 256 + threadIdx.x;   // < 2^20
    float s;
    if (USE_PART) {
        s = g[idx];
#pragma unroll
        for (int b = 1; b < NV / VB; ++b)
            s += g[(size_t)b * NE1 + idx];
    } else {
        s = g[idx];
    }
    const float p = 1.0f / (1.0f + __expf(-s));
    out1[idx] = x[idx] * p;
}

extern "C" void kernel_launch(void* const* d_in, const int* in_sizes, int n_in,
                              void* d_out, int out_size, void* d_ws, size_t ws_size,
                              hipStream_t stream)
{
    const float* x  = (const float*)d_in[0];
    const float* xo = (const float*)d_in[1];
    const float* A  = (const float*)d_in[2];
    const float* w1 = (const float*)d_in[3];
    const float* b1 = (const float*)d_in[4];
    const float* w2 = (const float*)d_in[5];
    const float* b2 = (const float*)d_in[6];
    const float* w3 = (const float*)d_in[7];
    const float* b3 = (const float*)d_in[8];
    const float* wo = (const float*)d_in[9];
    const float* bo = (const float*)d_in[10];

    float* out1 = (float*)d_out;
    float* Aout = (float*)d_out + NE1;

    float* xoc  = (float*)d_ws;                 // 4 MB
    float* gbuf = (float*)d_ws + NE1;           // partials (32 MB) or post (4 MB)

    // Deterministic host-side choice: private gate-partial slices (no global
    // atomics) when the workspace is large enough; else atomic fallback.
    const bool use_part =
        ws_size >= (size_t)(NE1 + (NV / VB) * NE1) * sizeof(float);

    k1_xoc<<<NE1 / 256, 256, 0, stream>>>(xo, wo, bo, xoc);
    if (use_part) {
        k2_mfma<true><<<dim3(NV / VB, 64), 256, 0, stream>>>(
            A, w1, b1, w2, b2, w3, b3, xoc, Aout, gbuf);
        k3_gate<true><<<NE1 / 256, 256, 0, stream>>>(x, gbuf, out1);
    } else {
        hipMemsetAsync(gbuf, 0, (size_t)NE1 * sizeof(float), stream);
        k2_mfma<false><<<dim3(NV / VB, 64), 256, 0, stream>>>(
            A, w1, b1, w2, b2, w3, b3, xoc, Aout, gbuf);
        k3_gate<false><<<NE1 / 256, 256, 0, stream>>>(x, gbuf, out1);
    }
}

// Round 8
// 263.111 us; speedup vs baseline: 1.5925x; 1.0640x over previous
//
#include <hip/hip_runtime.h>
#include <hip/hip_bf16.h>

#define NV 256                 // V
#define NC 64                  // C_OUT
#define VW 65536               // V*V
#define NE1 1048576            // N*C*V = 2^20
#define VB 32                  // v-chunk per block -> grid 8x64 = 512 = 2/CU

typedef __attribute__((ext_vector_type(8))) short bf16x8;   // 8 bf16 = 4 VGPRs
typedef __attribute__((ext_vector_type(16))) float f32x16;  // MFMA 32x32 acc
typedef __attribute__((ext_vector_type(4))) float f32x4;
typedef __attribute__((ext_vector_type(2))) unsigned int uint2v;

union U4 { unsigned int u[4]; bf16x8 v8; };

static __device__ __forceinline__ short f2bf(float x) {     // weights only
    union { __hip_bfloat16 b; short s; } u;
    u.b = __float2bfloat16(x);
    return u.s;
}
// one-inst RNE pack of two f32 -> 2xbf16
static __device__ __forceinline__ unsigned int cvt_pk_bf16(float a, float b) {
    unsigned int r;
    asm("v_cvt_pk_bf16_f32 %0, %1, %2" : "=v"(r) : "v"(a), "v"(b));
    return r;
}

// ---------------------------------------------------------------------------
// k1: xo_c[n][c][v] = bo[c] + sum_i wo[c][i] * xo[n][i][v]
// ---------------------------------------------------------------------------
__global__ __launch_bounds__(256) void k1_xoc(
    const float* __restrict__ xo, const float* __restrict__ wo,
    const float* __restrict__ bo, float* __restrict__ xoc)
{
    const int idx = blockIdx.x * 256 + threadIdx.x;   // < 2^20
    const int v = idx & 255;
    const int c = (idx >> 8) & 63;
    const int n = idx >> 14;
    const float* xon = xo + (size_t)n * 64 * NV;
    const float* wrow = wo + c * 64;                  // block-uniform -> s_load
    float s = bo[c];
#pragma unroll
    for (int i = 0; i < 64; ++i)
        s = fmaf(wrow[i], xon[i * NV + v], s);
    xoc[idx] = s;
}

// ---------------------------------------------------------------------------
// k2: math pipeline frozen from R6/R7 (L1 scalar SGPR-weights; L2+L3 on
// 32x32x16 bf16 MFMA with permlane32_swap fragment assembly; bias as MFMA
// C-seed). NEW output path: epilogue writes sigmoid values to a 64KB LDS
// tile stage[c][w] (2-way bank alias = free); after a barrier each wave
// streams COMPLETE (c,v) rows as 1KB nontemporal dwordx4 bursts (16 VMEM
// insts/thread/vi vs 64 scalar stores). Block = 4 waves x VB=32 v;
// grid = (8, 64) = 512 blocks = 2 resident/CU.
// ---------------------------------------------------------------------------
template <bool USE_PART>
__global__ __launch_bounds__(256) void k2_mfma(
    const float* __restrict__ A,
    const float* __restrict__ w1, const float* __restrict__ b1,
    const float* __restrict__ w2, const float* __restrict__ b2,
    const float* __restrict__ w3, const float* __restrict__ b3,
    const float* __restrict__ xoc,
    float* __restrict__ Aout, float* __restrict__ gout)
{
    __shared__ float stage[NC * NV];             // 64 KB: [c][w] for one v
    __shared__ float xocs[NC][VB];               // 8 KB

    const int t    = threadIdx.x;
    const int wt   = t >> 6;
    const int lane = t & 63;
    const int lo   = lane & 31;
    const int hi   = lane >> 5;
    const int vbase = blockIdx.x * VB;
    const int n    = blockIdx.y;
    const int w0   = wt << 6;

    for (int e = t; e < NC * VB; e += 256) {
        const int c = e >> 5, j = e & (VB - 1);
        xocs[c][j] = xoc[(size_t)n * (NC * NV) + c * NV + vbase + j];
    }
    __syncthreads();

    // W3 A-fragments: lane(lo,hi) holds w3[c=32ct+lo][k=16h+8hi+e]
    bf16x8 af[2][2];
#pragma unroll
    for (int ct = 0; ct < 2; ++ct)
#pragma unroll
        for (int h = 0; h < 2; ++h) {
            const float* wp = w3 + ((ct << 5) + lo) * 32 + (h << 4) + (hi << 3);
            bf16x8 pk;
#pragma unroll
            for (int e = 0; e < 8; ++e) pk[e] = f2bf(wp[e]);
            af[ct][h] = pk;
        }
    // W2 A-fragment: lane(lo,hi) holds w2[row=lo][k=8hi+e]  (K=16)
    bf16x8 af2;
#pragma unroll
    for (int e = 0; e < 8; ++e) af2[e] = f2bf(w2[lo * 16 + (hi << 3) + e]);

    // layer-3 bias as accumulator seed: dinit[ct][r] = b3[c(ct,r,hi)]
    f32x16 dinit[2];
#pragma unroll
    for (int ct = 0; ct < 2; ++ct)
#pragma unroll
        for (int r = 0; r < 16; ++r)
            dinit[ct][r] = b3[(ct << 5) + (r & 3) + ((r >> 2) << 3) + (hi << 2)];

    float gacc[2][2][16];
#pragma unroll
    for (int ct = 0; ct < 2; ++ct)
#pragma unroll
        for (int T = 0; T < 2; ++T)
#pragma unroll
            for (int r = 0; r < 16; ++r) gacc[ct][T][r] = 0.0f;

    const float* An  = A    + (size_t)n * 6 * VW;
    float*       Aon = Aout + (size_t)n * NC * VW;
    const float NLOG2E = -1.4426950408889634f;

    // software prefetch of the 5 A-planes for vi=0
    const float* ap0 = An + (size_t)vbase * NV + w0 + lane;
    float a0 = ap0[0], a1 = ap0[VW], a2 = ap0[2 * VW],
          a3 = ap0[3 * VW], a4 = ap0[4 * VW];

    for (int vi = 0; vi < VB; ++vi) {
        const int v = vbase + vi;

        const int vn = (vi + 1 < VB) ? (vi + 1) : vi;
        const float* apn = ap0 + (size_t)vn * NV;
        const float na0 = apn[0], na1 = apn[VW], na2 = apn[2 * VW],
                    na3 = apn[3 * VW], na4 = apn[4 * VW];

        // ===== layer 1 (5->16), scalar; weights are SGPR =====
        unsigned int h1p[8];
#pragma unroll
        for (int m = 0; m < 8; ++m) {
            float sa = b1[2 * m];
            float sb = b1[2 * m + 1];
            sa = fmaf(w1[(2 * m) * 5 + 0], a0, sa);
            sa = fmaf(w1[(2 * m) * 5 + 1], a1, sa);
            sa = fmaf(w1[(2 * m) * 5 + 2], a2, sa);
            sa = fmaf(w1[(2 * m) * 5 + 3], a3, sa);
            sa = fmaf(w1[(2 * m) * 5 + 4], a4, sa);
            sb = fmaf(w1[(2 * m + 1) * 5 + 0], a0, sb);
            sb = fmaf(w1[(2 * m + 1) * 5 + 1], a1, sb);
            sb = fmaf(w1[(2 * m + 1) * 5 + 2], a2, sb);
            sb = fmaf(w1[(2 * m + 1) * 5 + 3], a3, sb);
            sb = fmaf(w1[(2 * m + 1) * 5 + 4], a4, sb);
            h1p[m] = cvt_pk_bf16(fmaxf(sa, 0.0f), fmaxf(sb, 0.0f));
        }

        // ===== layer 2 (16->32) on MFMA =====
        U4 b1T0, b1T1;
#pragma unroll
        for (int j = 0; j < 4; ++j) {
            uint2v r = __builtin_amdgcn_permlane32_swap(h1p[j], h1p[4 + j],
                                                        false, false);
            b1T0.u[j] = r.x;
            b1T1.u[j] = r.y;
        }
        f32x16 d20, d21;
#pragma unroll
        for (int r = 0; r < 16; ++r) {
            const float bv = b2[(r & 3) + ((r >> 2) << 3) + (hi << 2)];
            d20[r] = bv; d21[r] = bv;
        }
        d20 = __builtin_amdgcn_mfma_f32_32x32x16_bf16(af2, b1T0.v8, d20, 0, 0, 0);
        d21 = __builtin_amdgcn_mfma_f32_32x32x16_bf16(af2, b1T1.v8, d21, 0, 0, 0);

        unsigned int p[8], q[8];
#pragma unroll
        for (int j = 0; j < 8; ++j) {
            p[j] = cvt_pk_bf16(fmaxf(d20[2 * j], 0.0f), fmaxf(d20[2 * j + 1], 0.0f));
            q[j] = cvt_pk_bf16(fmaxf(d21[2 * j], 0.0f), fmaxf(d21[2 * j + 1], 0.0f));
        }
        U4 b3f[2][2];
#pragma unroll
        for (int h = 0; h < 2; ++h) {
            uint2v r02 = __builtin_amdgcn_permlane32_swap(p[4 * h + 0], p[4 * h + 2], false, false);
            uint2v r13 = __builtin_amdgcn_permlane32_swap(p[4 * h + 1], p[4 * h + 3], false, false);
            b3f[0][h].u[0] = r02.x; b3f[0][h].u[2] = r02.y;
            b3f[0][h].u[1] = r13.x; b3f[0][h].u[3] = r13.y;
            uint2v s02 = __builtin_amdgcn_permlane32_swap(q[4 * h + 0], q[4 * h + 2], false, false);
            uint2v s13 = __builtin_amdgcn_permlane32_swap(q[4 * h + 1], q[4 * h + 3], false, false);
            b3f[1][h].u[0] = s02.x; b3f[1][h].u[2] = s02.y;
            b3f[1][h].u[1] = s13.x; b3f[1][h].u[3] = s13.y;
        }

        // ===== layer 3 MFMA; epilogue -> LDS stage tile ====================
#pragma unroll
        for (int ct = 0; ct < 2; ++ct) {
            f32x16 d0 = dinit[ct], d1 = dinit[ct];
            d0 = __builtin_amdgcn_mfma_f32_32x32x16_bf16(af[ct][0], b3f[0][0].v8, d0, 0, 0, 0);
            d0 = __builtin_amdgcn_mfma_f32_32x32x16_bf16(af[ct][1], b3f[0][1].v8, d0, 0, 0, 0);
            d1 = __builtin_amdgcn_mfma_f32_32x32x16_bf16(af[ct][0], b3f[1][0].v8, d1, 0, 0, 0);
            d1 = __builtin_amdgcn_mfma_f32_32x32x16_bf16(af[ct][1], b3f[1][1].v8, d1, 0, 0, 0);
#pragma unroll
            for (int r = 0; r < 16; ++r) {
                // C/D: col=lane&31 (=w within tile), row c depends on hi
                const int c = (ct << 5) + (r & 3) + ((r >> 2) << 3) + (hi << 2);
                const float vx = __builtin_amdgcn_rcpf(
                    1.0f + __builtin_amdgcn_exp2f(d0[r] * NLOG2E));
                const float vy = __builtin_amdgcn_rcpf(
                    1.0f + __builtin_amdgcn_exp2f(d1[r] * NLOG2E));
                stage[c * NV + w0 + lo]      = vx;   // T0 tile, bank=lo (2-way)
                stage[c * NV + w0 + 32 + lo] = vy;   // T1 tile
                gacc[ct][0][r] = fmaf(xocs[c][vi], vx, gacc[ct][0][r]);
                gacc[ct][1][r] = fmaf(xocs[c][vi], vy, gacc[ct][1][r]);
            }
        }
        __syncthreads();

        // ===== sweep: each wave stores full (c,v) rows as 1KB dwordx4 ======
#pragma unroll
        for (int k = 0; k < 16; ++k) {
            const int c = (k << 2) + wt;
            const f32x4 val = *(const f32x4*)&stage[c * NV + (lane << 2)];
            __builtin_nontemporal_store(
                val, (f32x4*)(Aon + (size_t)c * VW + (size_t)v * NV + (lane << 2)));
        }
        __syncthreads();   // protect stage before next vi's writes

        a0 = na0; a1 = na1; a2 = na2; a3 = na3; a4 = na4;
    }

    // ---- gate partials: per-block private slice (plain) or atomic pass
    if (USE_PART) {
        float* gp = gout + (size_t)blockIdx.x * NE1
                         + (size_t)n * (NC * NV) + w0;
#pragma unroll
        for (int ct = 0; ct < 2; ++ct)
#pragma unroll
            for (int T = 0; T < 2; ++T)
#pragma unroll
                for (int r = 0; r < 16; ++r) {
                    const int c = (ct << 5) + (r & 3) + ((r >> 2) << 3) + (hi << 2);
                    gp[c * NV + (T << 5) + lo] = gacc[ct][T][r];
                }
    } else {
        float* pn = gout + (size_t)n * (NC * NV) + w0;
#pragma unroll
        for (int ct = 0; ct < 2; ++ct)
#pragma unroll
            for (int T = 0; T < 2; ++T)
#pragma unroll
                for (int r = 0; r < 16; ++r) {
                    const int c = (ct << 5) + (r & 3) + ((r >> 2) << 3) + (hi << 2);
                    atomicAdd(pn + c * NV + (T << 5) + lo, gacc[ct][T][r]);
                }
    }
}

// ---------------------------------------------------------------------------
// k3: out1 = x * sigmoid(sum of gate partials)
// ---------------------------------------------------------------------------
template <bool USE_PART>
__global__ __launch_bounds__(256) void k3_gate(
    const float* __restrict__ x, const float* __restrict__ g,
    float* __restrict__ out1)
{
    const int idx = blockIdx.x * 256 + threadIdx.x;   // < 2^20
    float s;
    if (USE_PART) {
        s = g[idx];
#pragma unroll
        for (int b = 1; b < NV / VB; ++b)
            s += g[(size_t)b * NE1 + idx];
    } else {
        s = g[idx];
    }
    const float p = 1.0f / (1.0f + __expf(-s));
    out1[idx] = x[idx] * p;
}

extern "C" void kernel_launch(void* const* d_in, const int* in_sizes, int n_in,
                              void* d_out, int out_size, void* d_ws, size_t ws_size,
                              hipStream_t stream)
{
    const float* x  = (const float*)d_in[0];
    const float* xo = (const float*)d_in[1];
    const float* A  = (const float*)d_in[2];
    const float* w1 = (const float*)d_in[3];
    const float* b1 = (const float*)d_in[4];
    const float* w2 = (const float*)d_in[5];
    const float* b2 = (const float*)d_in[6];
    const float* w3 = (const float*)d_in[7];
    const float* b3 = (const float*)d_in[8];
    const float* wo = (const float*)d_in[9];
    const float* bo = (const float*)d_in[10];

    float* out1 = (float*)d_out;
    float* Aout = (float*)d_out + NE1;

    float* xoc  = (float*)d_ws;                 // 4 MB
    float* gbuf = (float*)d_ws + NE1;           // partials (32 MB) or post (4 MB)

    const bool use_part =
        ws_size >= (size_t)(NE1 + (NV / VB) * NE1) * sizeof(float);

    k1_xoc<<<NE1 / 256, 256, 0, stream>>>(xo, wo, bo, xoc);
    if (use_part) {
        k2_mfma<true><<<dim3(NV / VB, 64), 256, 0, stream>>>(
            A, w1, b1, w2, b2, w3, b3, xoc, Aout, gbuf);
        k3_gate<true><<<NE1 / 256, 256, 0, stream>>>(x, gbuf, out1);
    } else {
        hipMemsetAsync(gbuf, 0, (size_t)NE1 * sizeof(float), stream);
        k2_mfma<false><<<dim3(NV / VB, 64), 256, 0, stream>>>(
            A, w1, b1, w2, b2, w3, b3, xoc, Aout, gbuf);
        k3_gate<false><<<NE1 / 256, 256, 0, stream>>>(x, gbuf, out1);
    }
}